// Round 1
// baseline (289.964 us; speedup 1.0000x reference)
//
#include <hip/hip_runtime.h>
#include <stdint.h>

// Round 0: correct structured baseline.
//   K1 prep_weights: W[k][n] fp32 -> Wt[w][n][k] bf16 (LDS tile transpose)
//   K2 qkv_gemm:     sigmoid(X@W) -> Qb,Kb bf16 row-major; V stored transposed Vt[b][d][s]
//   K3 attn:         causal (j<i) attention, unnormalized exp accumulation (scores>0 bounded
//                    by 22.63 so no max-tracking needed), divide by row-sum at end.
// All MFMA: v_mfma_f32_16x16x32_bf16.  All LDS tiles XOR-swizzled: byte ^= (row&7)<<4.

typedef __attribute__((ext_vector_type(4))) float f32x4;
typedef __attribute__((ext_vector_type(8))) short short8;
typedef __attribute__((ext_vector_type(4))) short short4b;

__device__ __forceinline__ short f2bf(float f) {
    union { float f; uint32_t u; } v; v.f = f;
    uint32_t r = (v.u + 0x7FFFu + ((v.u >> 16) & 1u)) >> 16;   // RNE
    return (short)r;
}
__device__ __forceinline__ float bf2f(short s) {
    union { uint32_t u; float f; } v; v.u = ((uint32_t)(uint16_t)s) << 16; return v.f;
}
__device__ __forceinline__ float sigm(float x) { return 1.0f / (1.0f + __expf(-x)); }

// ---------------------------------------------------------------- K1: weights
__global__ __launch_bounds__(256) void prep_weights(
    const float* __restrict__ Wq, const float* __restrict__ Wv, const float* __restrict__ Wk,
    short* __restrict__ Wt)
{
    __shared__ float T[64 * 68];
    int bid = blockIdx.x;
    int w = bid >> 6;                 // 0..2
    int tile = bid & 63;
    int n0 = (tile & 7) * 64;
    int k0 = (tile >> 3) * 64;
    const float* W = (w == 0) ? Wq : (w == 1) ? Wv : Wk;
    int t = threadIdx.x;
    int tr = t >> 4, tc = t & 15;
    for (int rr = 0; rr < 4; ++rr) {
        int row = rr * 16 + tr;       // k-local
        float4 v = *reinterpret_cast<const float4*>(&W[(size_t)(k0 + row) * 512 + n0 + tc * 4]);
        T[row * 68 + tc * 4 + 0] = v.x;
        T[row * 68 + tc * 4 + 1] = v.y;
        T[row * 68 + tc * 4 + 2] = v.z;
        T[row * 68 + tc * 4 + 3] = v.w;
    }
    __syncthreads();
    for (int wr = 0; wr < 4; ++wr) {
        int nl = wr * 16 + tr;        // n-local
        short4b o;
        for (int i = 0; i < 4; ++i) o[i] = f2bf(T[(tc * 4 + i) * 68 + nl]);
        *reinterpret_cast<short4b*>(&Wt[((size_t)(w * 512 + n0 + nl)) * 512 + k0 + tc * 4]) = o;
    }
}

// ---------------------------------------------------------------- K2: QKV GEMM
// grid 1536: bx&127 = m-tile(128 rows), bx>>7 = w*4+ntile
__global__ __launch_bounds__(256) void qkv_gemm(
    const float* __restrict__ X,     // [16384][512] fp32
    const short* __restrict__ Wt,    // [3][512 n][512 k] bf16
    short* __restrict__ Qb, short* __restrict__ Kb, short* __restrict__ VtG)
{
    __shared__ short SMEM[128 * 128];          // As[128][64] | Bs[128][64]; Ts aliases after loop
    short* As = SMEM;
    short* Bs = SMEM + 128 * 64;

    int bx = blockIdx.x;
    int mt = bx & 127;
    int y = bx >> 7;
    int w = y >> 2, nt = y & 3;
    int m0 = mt * 128, n0 = nt * 128;

    int tid = threadIdx.x;
    int wid = tid >> 6, lane = tid & 63;
    int wr = wid >> 1, wc = wid & 1;
    int ln = lane & 15, hi = lane >> 4;

    f32x4 acc[4][4];
    for (int i = 0; i < 4; ++i) for (int j = 0; j < 4; ++j) acc[i][j] = {0.f, 0.f, 0.f, 0.f};

    const short* WtW = Wt + (size_t)w * 512 * 512;

    for (int ko = 0; ko < 8; ++ko) {
        int k0 = ko * 64;
        __syncthreads();
        // A: X fp32 -> bf16 swizzled [128][64]
        for (int j = 0; j < 8; ++j) {
            int c = j * 256 + tid;               // 2048 float4 chunks
            int row = c >> 4, col4 = c & 15;
            float4 v = *reinterpret_cast<const float4*>(&X[(size_t)(m0 + row) * 512 + k0 + col4 * 4]);
            short4b s;
            s[0] = f2bf(v.x); s[1] = f2bf(v.y); s[2] = f2bf(v.z); s[3] = f2bf(v.w);
            *reinterpret_cast<short4b*>(&As[row * 64 + ((col4 * 4) ^ ((row & 7) << 3))]) = s;
        }
        // B: Wt bf16 [128 n][64 k] swizzled
        for (int j = 0; j < 4; ++j) {
            int c = j * 256 + tid;               // 1024 16B chunks
            int row = c >> 3, col8 = c & 7;
            short8 v = *reinterpret_cast<const short8*>(&WtW[(size_t)(n0 + row) * 512 + k0 + col8 * 8]);
            *reinterpret_cast<short8*>(&Bs[row * 64 + ((col8 * 8) ^ ((row & 7) << 3))]) = v;
        }
        __syncthreads();
        for (int kk = 0; kk < 2; ++kk) {
            int kof = kk * 32 + hi * 8;
            int sw = (ln & 7) << 3;
            short8 af[4], bf[4];
            for (int mf = 0; mf < 4; ++mf)
                af[mf] = *reinterpret_cast<const short8*>(&As[(wr * 64 + mf * 16 + ln) * 64 + (kof ^ sw)]);
            for (int nf = 0; nf < 4; ++nf)
                bf[nf] = *reinterpret_cast<const short8*>(&Bs[(wc * 64 + nf * 16 + ln) * 64 + (kof ^ sw)]);
            for (int mf = 0; mf < 4; ++mf)
                for (int nf = 0; nf < 4; ++nf)
                    acc[mf][nf] = __builtin_amdgcn_mfma_f32_16x16x32_bf16(af[mf], bf[nf], acc[mf][nf], 0, 0, 0);
        }
    }
    __syncthreads();

    if (w < 2) {
        short* O = (w == 0) ? Qb : Kb;
        for (int mf = 0; mf < 4; ++mf)
            for (int nf = 0; nf < 4; ++nf)
                for (int j = 0; j < 4; ++j) {
                    int row = m0 + wr * 64 + mf * 16 + hi * 4 + j;
                    int col = n0 + wc * 64 + nf * 16 + ln;
                    O[(size_t)row * 512 + col] = f2bf(sigm(acc[mf][nf][j]));
                }
    } else {
        // V: transpose via LDS, store Vt[b][d][s]
        for (int mf = 0; mf < 4; ++mf)
            for (int nf = 0; nf < 4; ++nf)
                for (int j = 0; j < 4; ++j) {
                    int ml = wr * 64 + mf * 16 + hi * 4 + j;       // s-local
                    int nl = wc * 64 + nf * 16 + ln;               // d-local
                    SMEM[nl * 128 + (ml ^ ((nl & 7) << 3))] = f2bf(sigm(acc[mf][nf][j]));
                }
        __syncthreads();
        int bb = m0 >> 11;
        int s0 = m0 & 2047;
        int d = tid >> 1, h = tid & 1;
        for (int i = 0; i < 8; ++i) {
            int s8 = h * 64 + i * 8;
            short8 v = *reinterpret_cast<const short8*>(&SMEM[d * 128 + (s8 ^ ((d & 7) << 3))]);
            *reinterpret_cast<short8*>(&VtG[((size_t)(bb * 512 + n0 + d)) * 2048 + s0 + s8]) = v;
        }
    }
}

// ---------------------------------------------------------------- K3: attention
// 256 blocks = 8 batches x 32 pairs. Block does q-tiles {p, 63-p} (32 rows each),
// KV-tile 64 -> uniform 33 steps/block. 8 waves: QK^T frag (fr=w>>2, fc=w&3);
// PV: wave owns D cols [w*64, w*64+64).
__global__ __launch_bounds__(512) void attn_kernel(
    const short* __restrict__ Qb, const short* __restrict__ Kb, const short* __restrict__ VtG,
    float* __restrict__ Out)
{
    __shared__ short Ks[64 * 512];     // [kv][k] swizzled
    __shared__ short Vts[512 * 64];    // [d][kv] swizzled
    __shared__ short Ps[32 * 64];      // [q][kv] bf16 swizzled
    __shared__ float lsum[4][32];      // per-fc row partial sums (single writer)

    const float scale = 0.044194173824159216f;   // 1/sqrt(512)

    int bid = blockIdx.x;
    int b = bid >> 5, pair = bid & 31;

    int tid = threadIdx.x;
    int w = tid >> 6, lane = tid & 63;
    int ln = lane & 15, hi = lane >> 4;
    int fr = w >> 2, fc = w & 3;

    const size_t bQK = (size_t)b * 2048 * 512;
    const size_t bV  = (size_t)b * 512 * 2048;

    for (int half = 0; half < 2; ++half) {
        int t = (half == 0) ? pair : 63 - pair;
        int q0 = t * 32;
        int nsteps = t / 2 + 1;

        __syncthreads();                           // prior normalize done before re-zero
        if (tid < 128) ((float*)lsum)[tid] = 0.f;

        // Q fragments in registers: rows q0 + fr*16 + ln, all 16 k-steps
        short8 qf[16];
        {
            const short* qrow = Qb + bQK + (size_t)(q0 + fr * 16 + ln) * 512;
            for (int ks = 0; ks < 16; ++ks)
                qf[ks] = *reinterpret_cast<const short8*>(&qrow[ks * 32 + hi * 8]);
        }
        f32x4 acco[2][4];
        for (int i = 0; i < 2; ++i) for (int j = 0; j < 4; ++j) acco[i][j] = {0.f, 0.f, 0.f, 0.f};

        for (int kt = 0; kt < nsteps; ++kt) {
            int kv0 = kt * 64;
            // stage K [64][512]
            for (int j = 0; j < 8; ++j) {
                int c = j * 512 + tid;
                int row = c >> 6, sc = (c & 63) * 8;
                short8 v = *reinterpret_cast<const short8*>(&Kb[bQK + (size_t)(kv0 + row) * 512 + sc]);
                *reinterpret_cast<short8*>(&Ks[row * 512 + (sc ^ ((row & 7) << 3))]) = v;
            }
            // stage V^T [512][64]
            for (int j = 0; j < 8; ++j) {
                int c = j * 512 + tid;
                int d = c >> 3, sc = (c & 7) * 8;
                short8 v = *reinterpret_cast<const short8*>(&VtG[bV + (size_t)d * 2048 + kv0 + sc]);
                *reinterpret_cast<short8*>(&Vts[d * 64 + (sc ^ ((d & 7) << 3))]) = v;
            }
            __syncthreads();

            // QK^T, full K=512
            f32x4 sacc = {0.f, 0.f, 0.f, 0.f};
            {
                const short* kbase = &Ks[(fc * 16 + ln) * 512];
                int sw = (ln & 7) << 3;
                for (int ks = 0; ks < 16; ++ks) {
                    short8 kf = *reinterpret_cast<const short8*>(&kbase[(ks * 32 + hi * 8) ^ sw]);
                    sacc = __builtin_amdgcn_mfma_f32_16x16x32_bf16(qf[ks], kf, sacc, 0, 0, 0);
                }
            }
            // mask (strict j<i), exp, P->LDS(bf16), row-sum partials
            {
                int jcol = kv0 + fc * 16 + ln;
                float ps[4];
                for (int j = 0; j < 4; ++j) {
                    int irow = q0 + fr * 16 + hi * 4 + j;
                    float p = (jcol < irow) ? __expf(sacc[j] * scale) : 0.f;
                    short h = f2bf(p);
                    int r = fr * 16 + hi * 4 + j;
                    Ps[r * 64 + ((fc * 16 + ln) ^ ((r & 7) << 3))] = h;
                    ps[j] = bf2f(h);               // keep numerator/denominator consistent
                }
                for (int j = 0; j < 4; ++j) {
                    float s = ps[j];
                    s += __shfl_xor(s, 1);
                    s += __shfl_xor(s, 2);
                    s += __shfl_xor(s, 4);
                    s += __shfl_xor(s, 8);
                    if (ln == 0) lsum[fc][fr * 16 + hi * 4 + j] += s;   // unique writer
                }
            }
            __syncthreads();

            // PV: O[32][w*64..+64] += P[32][64] * V[64][D-slice]
            for (int kst = 0; kst < 2; ++kst) {
                short8 pa[2];
                for (int rf = 0; rf < 2; ++rf) {
                    int ar = rf * 16 + ln;
                    pa[rf] = *reinterpret_cast<const short8*>(
                        &Ps[ar * 64 + ((kst * 32 + hi * 8) ^ ((ar & 7) << 3))]);
                }
                for (int cf = 0; cf < 4; ++cf) {
                    int d = w * 64 + cf * 16 + ln;
                    short8 vb = *reinterpret_cast<const short8*>(
                        &Vts[d * 64 + ((kst * 32 + hi * 8) ^ ((d & 7) << 3))]);
                    acco[0][cf] = __builtin_amdgcn_mfma_f32_16x16x32_bf16(pa[0], vb, acco[0][cf], 0, 0, 0);
                    acco[1][cf] = __builtin_amdgcn_mfma_f32_16x16x32_bf16(pa[1], vb, acco[1][cf], 0, 0, 0);
                }
            }
            __syncthreads();
        }

        // normalize + store (row 0 of each batch -> zeros)
        for (int rf = 0; rf < 2; ++rf)
            for (int cf = 0; cf < 4; ++cf)
                for (int j = 0; j < 4; ++j) {
                    int rl = rf * 16 + hi * 4 + j;
                    int i = q0 + rl;
                    float denom = lsum[0][rl] + lsum[1][rl] + lsum[2][rl] + lsum[3][rl];
                    float val = (i == 0) ? 0.f : acco[rf][cf][j] / denom;
                    Out[((size_t)b * 2048 + i) * 512 + w * 64 + cf * 16 + ln] = val;
                }
    }
}

// ---------------------------------------------------------------- launch
extern "C" void kernel_launch(void* const* d_in, const int* in_sizes, int n_in,
                              void* d_out, int out_size, void* d_ws, size_t ws_size,
                              hipStream_t stream) {
    const float* X  = (const float*)d_in[0];
    const float* Wq = (const float*)d_in[1];
    const float* Wv = (const float*)d_in[2];
    const float* Wk = (const float*)d_in[3];
    float* Out = (float*)d_out;

    char* ws = (char*)d_ws;
    const size_t WT_BYTES = (size_t)3 * 512 * 512 * 2;        // 1.5 MB
    const size_t MAT_BYTES = (size_t)16384 * 512 * 2;         // 16 MB each
    short* Wt = (short*)ws;
    short* Qb = (short*)(ws + WT_BYTES);
    short* Kb = (short*)(ws + WT_BYTES + MAT_BYTES);
    short* Vt = (short*)(ws + WT_BYTES + 2 * MAT_BYTES);

    prep_weights<<<192, 256, 0, stream>>>(Wq, Wv, Wk, Wt);
    qkv_gemm<<<1536, 256, 0, stream>>>(X, Wt, Qb, Kb, Vt);
    attn_kernel<<<256, 512, 0, stream>>>(Qb, Kb, Vt, Out);
}

// Round 2
// 194.173 us; speedup vs baseline: 1.4933x; 1.4933x over previous
//
#include <hip/hip_runtime.h>
#include <stdint.h>

// Round 1: attn rewrite.
//  - bid&7 = batch -> all 32 blocks of a batch on one XCD (K+V = 4MB = L2 size)
//  - T14 async staging: global->regs issued early, regs->LDS written after the
//    post-PV barrier; raw s_barrier + lgkmcnt(0) (NOT __syncthreads, which drains vmcnt)
//  - T5 setprio around MFMA clusters
// K1/K2 unchanged from round 0.

typedef __attribute__((ext_vector_type(4))) float f32x4;
typedef __attribute__((ext_vector_type(8))) short short8;
typedef __attribute__((ext_vector_type(4))) short short4b;

__device__ __forceinline__ short f2bf(float f) {
    union { float f; uint32_t u; } v; v.f = f;
    uint32_t r = (v.u + 0x7FFFu + ((v.u >> 16) & 1u)) >> 16;   // RNE
    return (short)r;
}
__device__ __forceinline__ float bf2f(short s) {
    union { uint32_t u; float f; } v; v.u = ((uint32_t)(uint16_t)s) << 16; return v.f;
}
__device__ __forceinline__ float sigm(float x) { return 1.0f / (1.0f + __expf(-x)); }

// barrier WITHOUT vmcnt drain: LDS writes visible (lgkmcnt 0), global loads stay in flight
#define BAR() asm volatile("s_waitcnt lgkmcnt(0)\n\ts_barrier" ::: "memory")

// ---------------------------------------------------------------- K1: weights
__global__ __launch_bounds__(256) void prep_weights(
    const float* __restrict__ Wq, const float* __restrict__ Wv, const float* __restrict__ Wk,
    short* __restrict__ Wt)
{
    __shared__ float T[64 * 68];
    int bid = blockIdx.x;
    int w = bid >> 6;                 // 0..2
    int tile = bid & 63;
    int n0 = (tile & 7) * 64;
    int k0 = (tile >> 3) * 64;
    const float* W = (w == 0) ? Wq : (w == 1) ? Wv : Wk;
    int t = threadIdx.x;
    int tr = t >> 4, tc = t & 15;
    for (int rr = 0; rr < 4; ++rr) {
        int row = rr * 16 + tr;       // k-local
        float4 v = *reinterpret_cast<const float4*>(&W[(size_t)(k0 + row) * 512 + n0 + tc * 4]);
        T[row * 68 + tc * 4 + 0] = v.x;
        T[row * 68 + tc * 4 + 1] = v.y;
        T[row * 68 + tc * 4 + 2] = v.z;
        T[row * 68 + tc * 4 + 3] = v.w;
    }
    __syncthreads();
    for (int wr = 0; wr < 4; ++wr) {
        int nl = wr * 16 + tr;        // n-local
        short4b o;
        for (int i = 0; i < 4; ++i) o[i] = f2bf(T[(tc * 4 + i) * 68 + nl]);
        *reinterpret_cast<short4b*>(&Wt[((size_t)(w * 512 + n0 + nl)) * 512 + k0 + tc * 4]) = o;
    }
}

// ---------------------------------------------------------------- K2: QKV GEMM
__global__ __launch_bounds__(256) void qkv_gemm(
    const float* __restrict__ X,     // [16384][512] fp32
    const short* __restrict__ Wt,    // [3][512 n][512 k] bf16
    short* __restrict__ Qb, short* __restrict__ Kb, short* __restrict__ VtG)
{
    __shared__ short SMEM[128 * 128];
    short* As = SMEM;
    short* Bs = SMEM + 128 * 64;

    int bx = blockIdx.x;
    int mt = bx & 127;
    int y = bx >> 7;
    int w = y >> 2, nt = y & 3;
    int m0 = mt * 128, n0 = nt * 128;

    int tid = threadIdx.x;
    int wid = tid >> 6, lane = tid & 63;
    int wr = wid >> 1, wc = wid & 1;
    int ln = lane & 15, hi = lane >> 4;

    f32x4 acc[4][4];
    for (int i = 0; i < 4; ++i) for (int j = 0; j < 4; ++j) acc[i][j] = {0.f, 0.f, 0.f, 0.f};

    const short* WtW = Wt + (size_t)w * 512 * 512;

    for (int ko = 0; ko < 8; ++ko) {
        int k0 = ko * 64;
        __syncthreads();
        for (int j = 0; j < 8; ++j) {
            int c = j * 256 + tid;
            int row = c >> 4, col4 = c & 15;
            float4 v = *reinterpret_cast<const float4*>(&X[(size_t)(m0 + row) * 512 + k0 + col4 * 4]);
            short4b s;
            s[0] = f2bf(v.x); s[1] = f2bf(v.y); s[2] = f2bf(v.z); s[3] = f2bf(v.w);
            *reinterpret_cast<short4b*>(&As[row * 64 + ((col4 * 4) ^ ((row & 7) << 3))]) = s;
        }
        for (int j = 0; j < 4; ++j) {
            int c = j * 256 + tid;
            int row = c >> 3, col8 = c & 7;
            short8 v = *reinterpret_cast<const short8*>(&WtW[(size_t)(n0 + row) * 512 + k0 + col8 * 8]);
            *reinterpret_cast<short8*>(&Bs[row * 64 + ((col8 * 8) ^ ((row & 7) << 3))]) = v;
        }
        __syncthreads();
        for (int kk = 0; kk < 2; ++kk) {
            int kof = kk * 32 + hi * 8;
            int sw = (ln & 7) << 3;
            short8 af[4], bf[4];
            for (int mf = 0; mf < 4; ++mf)
                af[mf] = *reinterpret_cast<const short8*>(&As[(wr * 64 + mf * 16 + ln) * 64 + (kof ^ sw)]);
            for (int nf = 0; nf < 4; ++nf)
                bf[nf] = *reinterpret_cast<const short8*>(&Bs[(wc * 64 + nf * 16 + ln) * 64 + (kof ^ sw)]);
            for (int mf = 0; mf < 4; ++mf)
                for (int nf = 0; nf < 4; ++nf)
                    acc[mf][nf] = __builtin_amdgcn_mfma_f32_16x16x32_bf16(af[mf], bf[nf], acc[mf][nf], 0, 0, 0);
        }
    }
    __syncthreads();

    if (w < 2) {
        short* O = (w == 0) ? Qb : Kb;
        for (int mf = 0; mf < 4; ++mf)
            for (int nf = 0; nf < 4; ++nf)
                for (int j = 0; j < 4; ++j) {
                    int row = m0 + wr * 64 + mf * 16 + hi * 4 + j;
                    int col = n0 + wc * 64 + nf * 16 + ln;
                    O[(size_t)row * 512 + col] = f2bf(sigm(acc[mf][nf][j]));
                }
    } else {
        for (int mf = 0; mf < 4; ++mf)
            for (int nf = 0; nf < 4; ++nf)
                for (int j = 0; j < 4; ++j) {
                    int ml = wr * 64 + mf * 16 + hi * 4 + j;       // s-local
                    int nl = wc * 64 + nf * 16 + ln;               // d-local
                    SMEM[nl * 128 + (ml ^ ((nl & 7) << 3))] = f2bf(sigm(acc[mf][nf][j]));
                }
        __syncthreads();
        int bb = m0 >> 11;
        int s0 = m0 & 2047;
        int d = tid >> 1, h = tid & 1;
        for (int i = 0; i < 8; ++i) {
            int s8 = h * 64 + i * 8;
            short8 v = *reinterpret_cast<const short8*>(&SMEM[d * 128 + (s8 ^ ((d & 7) << 3))]);
            *reinterpret_cast<short8*>(&VtG[((size_t)(bb * 512 + n0 + d)) * 2048 + s0 + s8]) = v;
        }
    }
}

// ---------------------------------------------------------------- K3: attention
// 256 blocks: bid&7 = batch (XCD affinity: one batch's K+V = 4MB = one XCD L2),
// bid>>3 = pair p; block does q-tiles {p, 63-p} (32 rows), KVBLK=64 -> 33 steps.
// Async staging: global->regs issued during compute of prev tile; regs->LDS after barrier.
__global__ __launch_bounds__(512, 2) void attn_kernel(
    const short* __restrict__ Qb, const short* __restrict__ Kb, const short* __restrict__ VtG,
    float* __restrict__ Out)
{
    __shared__ short Ks[64 * 512];     // [kv][k] swizzled
    __shared__ short Vts[512 * 64];    // [d][kv] swizzled
    __shared__ short Ps[32 * 64];      // [q][kv] bf16 swizzled
    __shared__ float lsum[4][32];

    const float scale = 0.044194173824159216f;   // 1/sqrt(512)

    int bid = blockIdx.x;
    int b = bid & 7, pair = bid >> 3;

    int tid = threadIdx.x;
    int w = tid >> 6, lane = tid & 63;
    int ln = lane & 15, hi = lane >> 4;
    int fr = w >> 2, fc = w & 3;

    const size_t bQK = (size_t)b * 2048 * 512;
    const size_t bV  = (size_t)b * 512 * 2048;

    short8 kreg[8], vreg[8];

    for (int half = 0; half < 2; ++half) {
        int t = (half == 0) ? pair : 63 - pair;
        int q0 = t * 32;
        int nsteps = t / 2 + 1;

        BAR();                                     // prev half done (lsum reads, LDS reuse)
        if (tid < 128) ((float*)lsum)[tid] = 0.f;

        // Q fragments in registers
        short8 qf[16];
        {
            const short* qrow = Qb + bQK + (size_t)(q0 + fr * 16 + ln) * 512;
            for (int ks = 0; ks < 16; ++ks)
                qf[ks] = *reinterpret_cast<const short8*>(&qrow[ks * 32 + hi * 8]);
        }
        f32x4 acco[2][4];
        for (int i = 0; i < 2; ++i) for (int j = 0; j < 4; ++j) acco[i][j] = {0.f, 0.f, 0.f, 0.f};

        // prologue: issue loads for tile 0
        {
            for (int j = 0; j < 8; ++j) {
                int c = j * 512 + tid;
                int row = c >> 6, c8 = c & 63;
                kreg[j] = *reinterpret_cast<const short8*>(&Kb[bQK + (size_t)row * 512 + c8 * 8]);
            }
            for (int j = 0; j < 8; ++j) {
                int c = j * 512 + tid;
                int d = c >> 3, c8 = c & 7;
                vreg[j] = *reinterpret_cast<const short8*>(&VtG[bV + (size_t)d * 2048 + c8 * 8]);
            }
        }

        for (int kt = 0; kt < nsteps; ++kt) {
            BAR();                                 // all waves done with prev-tile LDS (PV)
            // write staged regs -> LDS (compiler inserts vmcnt waits on kreg/vreg use)
            for (int j = 0; j < 8; ++j) {
                int c = j * 512 + tid;
                int row = c >> 6, sc = (c & 63) * 8;
                *reinterpret_cast<short8*>(&Ks[row * 512 + (sc ^ ((row & 7) << 3))]) = kreg[j];
            }
            for (int j = 0; j < 8; ++j) {
                int c = j * 512 + tid;
                int d = c >> 3, sc = (c & 7) * 8;
                *reinterpret_cast<short8*>(&Vts[d * 64 + (sc ^ ((d & 7) << 3))]) = vreg[j];
            }
            BAR();                                 // K/V visible

            // issue next tile's loads (async, latency hides under QK^T+softmax+PV)
            if (kt + 1 < nsteps) {
                int kv0 = (kt + 1) * 64;
                for (int j = 0; j < 8; ++j) {
                    int c = j * 512 + tid;
                    int row = c >> 6, c8 = c & 63;
                    kreg[j] = *reinterpret_cast<const short8*>(&Kb[bQK + (size_t)(kv0 + row) * 512 + c8 * 8]);
                }
                for (int j = 0; j < 8; ++j) {
                    int c = j * 512 + tid;
                    int d = c >> 3, c8 = c & 7;
                    vreg[j] = *reinterpret_cast<const short8*>(&VtG[bV + (size_t)d * 2048 + (kt + 1) * 64 + c8 * 8]);
                }
            }

            int kv0 = kt * 64;
            // QK^T, full K=512
            f32x4 sacc = {0.f, 0.f, 0.f, 0.f};
            {
                const short* kbase = &Ks[(fc * 16 + ln) * 512];
                int sw = (ln & 7) << 3;
                __builtin_amdgcn_s_setprio(1);
                for (int ks = 0; ks < 16; ++ks) {
                    short8 kf = *reinterpret_cast<const short8*>(&kbase[(ks * 32 + hi * 8) ^ sw]);
                    sacc = __builtin_amdgcn_mfma_f32_16x16x32_bf16(qf[ks], kf, sacc, 0, 0, 0);
                }
                __builtin_amdgcn_s_setprio(0);
            }
            // mask (strict j<i), exp, P->LDS(bf16), row-sum partials
            {
                int jcol = kv0 + fc * 16 + ln;
                float ps[4];
                for (int j = 0; j < 4; ++j) {
                    int irow = q0 + fr * 16 + hi * 4 + j;
                    float p = (jcol < irow) ? __expf(sacc[j] * scale) : 0.f;
                    short h = f2bf(p);
                    int r = fr * 16 + hi * 4 + j;
                    Ps[r * 64 + ((fc * 16 + ln) ^ ((r & 7) << 3))] = h;
                    ps[j] = bf2f(h);
                }
                for (int j = 0; j < 4; ++j) {
                    float s = ps[j];
                    s += __shfl_xor(s, 1);
                    s += __shfl_xor(s, 2);
                    s += __shfl_xor(s, 4);
                    s += __shfl_xor(s, 8);
                    if (ln == 0) lsum[fc][fr * 16 + hi * 4 + j] += s;
                }
            }
            BAR();                                 // P visible

            // PV: O[32][w*64..+64] += P[32][64] * V[64][D-slice]
            __builtin_amdgcn_s_setprio(1);
            for (int kst = 0; kst < 2; ++kst) {
                short8 pa[2];
                for (int rf = 0; rf < 2; ++rf) {
                    int ar = rf * 16 + ln;
                    pa[rf] = *reinterpret_cast<const short8*>(
                        &Ps[ar * 64 + ((kst * 32 + hi * 8) ^ ((ar & 7) << 3))]);
                }
                for (int cf = 0; cf < 4; ++cf) {
                    int d = w * 64 + cf * 16 + ln;
                    short8 vb = *reinterpret_cast<const short8*>(
                        &Vts[d * 64 + ((kst * 32 + hi * 8) ^ ((d & 7) << 3))]);
                    acco[0][cf] = __builtin_amdgcn_mfma_f32_16x16x32_bf16(pa[0], vb, acco[0][cf], 0, 0, 0);
                    acco[1][cf] = __builtin_amdgcn_mfma_f32_16x16x32_bf16(pa[1], vb, acco[1][cf], 0, 0, 0);
                }
            }
            __builtin_amdgcn_s_setprio(0);
        }

        // normalize + store (row 0 of each batch -> zeros)
        for (int rf = 0; rf < 2; ++rf)
            for (int cf = 0; cf < 4; ++cf)
                for (int j = 0; j < 4; ++j) {
                    int rl = rf * 16 + hi * 4 + j;
                    int i = q0 + rl;
                    float denom = lsum[0][rl] + lsum[1][rl] + lsum[2][rl] + lsum[3][rl];
                    float val = (i == 0) ? 0.f : acco[rf][cf][j] / denom;
                    Out[((size_t)b * 2048 + i) * 512 + w * 64 + cf * 16 + ln] = val;
                }
    }
}

// ---------------------------------------------------------------- launch
extern "C" void kernel_launch(void* const* d_in, const int* in_sizes, int n_in,
                              void* d_out, int out_size, void* d_ws, size_t ws_size,
                              hipStream_t stream) {
    const float* X  = (const float*)d_in[0];
    const float* Wq = (const float*)d_in[1];
    const float* Wv = (const float*)d_in[2];
    const float* Wk = (const float*)d_in[3];
    float* Out = (float*)d_out;

    char* ws = (char*)d_ws;
    const size_t WT_BYTES = (size_t)3 * 512 * 512 * 2;        // 1.5 MB
    const size_t MAT_BYTES = (size_t)16384 * 512 * 2;         // 16 MB each
    short* Wt = (short*)ws;
    short* Qb = (short*)(ws + WT_BYTES);
    short* Kb = (short*)(ws + WT_BYTES + MAT_BYTES);
    short* Vt = (short*)(ws + WT_BYTES + 2 * MAT_BYTES);

    prep_weights<<<192, 256, 0, stream>>>(Wq, Wv, Wk, Wt);
    qkv_gemm<<<1536, 256, 0, stream>>>(X, Wt, Qb, Kb, Vt);
    attn_kernel<<<256, 512, 0, stream>>>(Qb, Kb, Vt, Out);
}